// Round 1
// 2633.809 us; speedup vs baseline: 1.1507x; 1.1507x over previous
//
#include <hip/hip_runtime.h>
#include <math.h>

#define NTH 256

__device__ __forceinline__ unsigned enc_f(float x){
  unsigned u = __float_as_uint(x);
  return (u & 0x80000000u) ? ~u : (u | 0x80000000u);
}
__device__ __forceinline__ float dec_f(unsigned v){
  unsigned u = (v & 0x80000000u) ? (v & 0x7FFFFFFFu) : ~v;
  return __uint_as_float(u);
}

// ---------------------------------------------------------------------------
// Node linear: out[N,DO] = x[N,DI] @ W[DI,DO] (+ bias)
// JSPLIT: waves per row-group; wave handles (row_group, j-chunk of DO/JSPLIT).
// Halves/quarters per-lane acc footprint -> higher occupancy. W reads stay
// wave-uniform s_loads (j0 forced to SGPR via readfirstlane).
// ---------------------------------------------------------------------------
template<int DI, int DIS, int DO, int DOS, int JSPLIT, int MINW>
__global__ __launch_bounds__(NTH, MINW) void node_linear_k(
    const float* __restrict__ x, const float* __restrict__ W,
    const float* __restrict__ bias, float* __restrict__ out, int N)
{
  constexpr int WPB = NTH / 64;        // waves per block
  constexpr int GPB = WPB / JSPLIT;    // row-groups per block
  constexpr int DOW = DO / JSPLIT;     // outputs per wave
  const int lane = threadIdx.x & 63;
  const int wave = threadIdx.x >> 6;
  const int group = blockIdx.x * GPB + (wave / JSPLIT);
  const int j0 = __builtin_amdgcn_readfirstlane((wave % JSPLIT) * DOW);
  const int row = group * 64 + lane;
  const bool valid = row < N;
  const int rr = valid ? row : (N - 1);
  const float* xr = x + (size_t)rr * DIS;

  float acc[DOW];
  if (bias != nullptr) {
    #pragma unroll
    for (int j = 0; j < DOW; j++) acc[j] = bias[j0 + j];
  } else {
    #pragma unroll
    for (int j = 0; j < DOW; j++) acc[j] = 0.f;
  }

  constexpr int K4 = DI & ~3;
  for (int k = 0; k < K4; k += 4) {
    float4 ev = *(const float4*)(xr + k);
    float ea[4] = {ev.x, ev.y, ev.z, ev.w};
    #pragma unroll
    for (int kk = 0; kk < 4; kk++) {
      const float* wr = W + (size_t)(k + kk) * DO + j0;
      #pragma unroll
      for (int j = 0; j < DOW; j++)
        acc[j] = fmaf(ea[kk], wr[j], acc[j]);
    }
  }
  #pragma unroll
  for (int k = K4; k < DI; k++) {
    float ev = xr[k];
    const float* wr = W + (size_t)k * DO + j0;
    #pragma unroll
    for (int j = 0; j < DOW; j++)
      acc[j] = fmaf(ev, wr[j], acc[j]);
  }

  if (valid) {
    float* orow = out + (size_t)row * DOS + j0;
    constexpr int J4 = DOW & ~3;
    #pragma unroll
    for (int j = 0; j < J4; j += 4)
      *(float4*)(orow + j) = make_float4(acc[j], acc[j+1], acc[j+2], acc[j+3]);
    #pragma unroll
    for (int j = J4; j < DOW; j++) orow[j] = acc[j];
  }
}

// ---------------------------------------------------------------------------
// Edge kernel: f = leaky_relu(xWni[src] + xWnj[dst] + e@Wf + bias)
// JSPLIT waves share an edge-group; each owns DO/JSPLIT outputs. Score needs
// a full-row dot with attn -> cross-wave LDS reduction, finalized by sub==0.
// ---------------------------------------------------------------------------
template<int DI, int DIS, int DO, int DOS, int JSPLIT, bool SCORE, int MINW>
__global__ __launch_bounds__(NTH, MINW) void edge_f_k(
    const float* __restrict__ efeat, const float* __restrict__ xWni,
    const float* __restrict__ xWnj, const float* __restrict__ Wf,
    const float* __restrict__ attn, const float* __restrict__ bias,
    const int* __restrict__ src, const int* __restrict__ dst,
    float* __restrict__ fout, float* __restrict__ score,
    unsigned* __restrict__ menc, int E)
{
  constexpr int WPB = NTH / 64;
  constexpr int GPB = WPB / JSPLIT;
  constexpr int DOW = DO / JSPLIT;
  const int lane = threadIdx.x & 63;
  const int wave = threadIdx.x >> 6;
  const int sub  = wave % JSPLIT;
  const int group = blockIdx.x * GPB + (wave / JSPLIT);
  const int j0 = __builtin_amdgcn_readfirstlane(sub * DOW);
  const int eidx = group * 64 + lane;
  const bool valid = eidx < E;
  const int ee = valid ? eidx : (E - 1);

  const int sn = src[ee];
  const int dn = dst[ee];
  const float* ar = xWni + (size_t)sn * DOS + j0;
  const float* br = xWnj + (size_t)dn * DOS + j0;

  float acc[DOW];
  constexpr int J4 = DOW & ~3;
  #pragma unroll
  for (int j = 0; j < J4; j += 4) {
    float4 a4 = *(const float4*)(ar + j);
    float4 b4 = *(const float4*)(br + j);
    acc[j+0] = bias[j0+j+0] + a4.x + b4.x;
    acc[j+1] = bias[j0+j+1] + a4.y + b4.y;
    acc[j+2] = bias[j0+j+2] + a4.z + b4.z;
    acc[j+3] = bias[j0+j+3] + a4.w + b4.w;
  }
  #pragma unroll
  for (int j = J4; j < DOW; j++)
    acc[j] = bias[j0+j] + ar[j] + br[j];

  const float* er = efeat + (size_t)ee * DIS;
  constexpr int K4 = DI & ~3;
  for (int k = 0; k < K4; k += 4) {
    float4 ev = *(const float4*)(er + k);
    float ea[4] = {ev.x, ev.y, ev.z, ev.w};
    #pragma unroll
    for (int kk = 0; kk < 4; kk++) {
      const float* wr = Wf + (size_t)(k + kk) * DO + j0;
      #pragma unroll
      for (int j = 0; j < DOW; j++)
        acc[j] = fmaf(ea[kk], wr[j], acc[j]);
    }
  }
  #pragma unroll
  for (int k = K4; k < DI; k++) {
    float ev = er[k];
    const float* wr = Wf + (size_t)k * DO + j0;
    #pragma unroll
    for (int j = 0; j < DOW; j++)
      acc[j] = fmaf(ev, wr[j], acc[j]);
  }

  float sc = 0.f;
  #pragma unroll
  for (int j = 0; j < DOW; j++) {
    float v = acc[j];
    v = (v > 0.f) ? v : 0.01f * v;
    acc[j] = v;
    if (SCORE) sc += v * attn[j0 + j];
  }

  if (valid) {
    float* orow = fout + (size_t)eidx * DOS + j0;
    #pragma unroll
    for (int j = 0; j < J4; j += 4)
      *(float4*)(orow + j) = make_float4(acc[j], acc[j+1], acc[j+2], acc[j+3]);
    #pragma unroll
    for (int j = J4; j < DOW; j++) orow[j] = acc[j];
  }

  if constexpr (SCORE && JSPLIT > 1) {
    __shared__ float scpart[WPB][64];
    scpart[wave][lane] = sc;
    __syncthreads();
    if (sub == 0 && valid) {
      float tot = sc;
      #pragma unroll
      for (int s = 1; s < JSPLIT; s++) tot += scpart[wave + s][lane];
      score[eidx] = tot;
      atomicMax(&menc[dn], enc_f(tot));
    }
  } else if constexpr (SCORE) {
    if (valid) {
      score[eidx] = sc;
      atomicMax(&menc[dn], enc_f(sc));
    }
  }
}

__global__ __launch_bounds__(NTH) void softmax_ex_k(float* __restrict__ score,
    const int* __restrict__ dst, const unsigned* __restrict__ menc,
    float* __restrict__ ssum, int E)
{
  int i = blockIdx.x * NTH + threadIdx.x;
  if (i < E) {
    int d = dst[i];
    float ex = expf(score[i] - dec_f(menc[d]));
    score[i] = ex;
    atomicAdd(&ssum[d], ex);
  }
}

__global__ __launch_bounds__(NTH) void softmax_norm_k(float* __restrict__ score,
    const float* __restrict__ ssum, const int* __restrict__ dst, int E)
{
  int i = blockIdx.x * NTH + threadIdx.x;
  if (i < E) score[i] = score[i] / ssum[dst[i]];
}

template<int DO, int HS, int OS>
__global__ __launch_bounds__(NTH) void scatter_h_k(const float* __restrict__ a,
    const int* __restrict__ src, const int* __restrict__ dst,
    const float* __restrict__ h, float* __restrict__ hout, int E)
{
  long long idx = (long long)blockIdx.x * NTH + threadIdx.x;
  if (idx < (long long)E * DO) {
    int e = (int)(idx / DO);
    int col = (int)(idx - (long long)e * DO);
    atomicAdd(&hout[(size_t)dst[e] * OS + col], h[(size_t)src[e] * HS + col] * a[e]);
  }
}

extern "C" void kernel_launch(void* const* d_in, const int* in_sizes, int n_in,
                              void* d_out, int out_size, void* d_ws, size_t ws_size,
                              hipStream_t stream)
{
  const float* x    = (const float*)d_in[0];
  const float* e    = (const float*)d_in[1];
  const int*   src  = (const int*)d_in[2];
  const int*   dst  = (const int*)d_in[3];
  const float* W_n1 = (const float*)d_in[4];   const float* b_n1  = (const float*)d_in[5];
  const float* W_ni1= (const float*)d_in[6];   const float* W_nj1 = (const float*)d_in[7];
  const float* W_f1 = (const float*)d_in[8];   const float* attn1 = (const float*)d_in[9];
  const float* bias1= (const float*)d_in[10];
  const float* W_n2 = (const float*)d_in[11];  const float* b_n2  = (const float*)d_in[12];
  const float* W_ni2= (const float*)d_in[13];  const float* W_nj2 = (const float*)d_in[14];
  const float* W_f2 = (const float*)d_in[15];  const float* attn2 = (const float*)d_in[16];
  const float* bias2= (const float*)d_in[17];
  const float* W_n3 = (const float*)d_in[18];  const float* b_n3  = (const float*)d_in[19];
  const float* W_ni3= (const float*)d_in[20];  const float* W_nj3 = (const float*)d_in[21];
  const float* W_f3 = (const float*)d_in[22];  const float* attn3 = (const float*)d_in[23];
  const float* bias3= (const float*)d_in[24];
  (void)W_n3; (void)b_n3;  // layer-3 node aggregation is dead (only f3 returned)

  const int N = in_sizes[0] / 128;
  const int E = in_sizes[2];

  float* ws = (float*)d_ws;
  size_t off = 0;
  float* fbuf1 = ws + off; off += (size_t)E * 128;   // f1 [E,128]
  float* fbuf2 = ws + off; off += (size_t)E * 32;    // f2 [E,30] padded to 32
  float* xWni  = ws + off; off += (size_t)N * 128;
  float* xWnj  = ws + off; off += (size_t)N * 128;
  float* hbuf  = ws + off; off += (size_t)N * 128;
  float* nodeA = ws + off; off += (size_t)N * 128;   // h_out layer1 [N,128]
  float* nodeB = ws + off; off += (size_t)N * 32;    // h_out layer2 [N,30] pad 32
  float* scoreb= ws + off; off += (size_t)E;         // score -> ex -> a (in place)
  unsigned* menc = (unsigned*)(ws + off); off += (size_t)N;
  float* sbuf  = ws + off; off += (size_t)N;

  const int groupsN = (N + 63) / 64;   // 64 rows per wave-group
  const int groupsE = (E + 63) / 64;
  const int gN2 = (groupsN + 1) / 2;   // JSPLIT=2: 2 groups/block
  const int gN4 = (groupsN + 3) / 4;   // JSPLIT=1: 4 groups/block
  const int gE2 = (groupsE + 1) / 2;
  const int gE4 = (groupsE + 3) / 4;
  const int gEe = (E + NTH - 1) / NTH;

  // ---------------- layer 1: di=128 -> do=128 (JSPLIT=2, acc[64]/lane) ----------------
  node_linear_k<128,128,128,128,2,4><<<gN2,NTH,0,stream>>>(x, W_ni1, nullptr, xWni, N);
  node_linear_k<128,128,128,128,2,4><<<gN2,NTH,0,stream>>>(x, W_nj1, nullptr, xWnj, N);
  node_linear_k<128,128,128,128,2,4><<<gN2,NTH,0,stream>>>(x, W_n1,  b_n1,   hbuf, N);
  hipMemsetAsync(menc, 0, (size_t)N * 4, stream);   // enc(-inf)=0 lower bound
  hipMemsetAsync(sbuf, 0, (size_t)N * 4, stream);
  hipMemsetAsync(nodeA, 0, (size_t)N * 128 * 4, stream);
  edge_f_k<128,128,128,128,2,true,4><<<gE2,NTH,0,stream>>>(e, xWni, xWnj, W_f1, attn1, bias1,
                                                           src, dst, fbuf1, scoreb, menc, E);
  softmax_ex_k<<<gEe,NTH,0,stream>>>(scoreb, dst, menc, sbuf, E);
  softmax_norm_k<<<gEe,NTH,0,stream>>>(scoreb, sbuf, dst, E);
  scatter_h_k<128,128,128><<<(int)(((long long)E*128 + NTH-1)/NTH),NTH,0,stream>>>(scoreb, src, dst, hbuf, nodeA, E);

  // ---------------- layer 2: di=128 -> do=30 (pad 32, JSPLIT=1) ----------------
  node_linear_k<128,128,30,32,1,5><<<gN4,NTH,0,stream>>>(nodeA, W_ni2, nullptr, xWni, N);
  node_linear_k<128,128,30,32,1,5><<<gN4,NTH,0,stream>>>(nodeA, W_nj2, nullptr, xWnj, N);
  node_linear_k<128,128,30,32,1,5><<<gN4,NTH,0,stream>>>(nodeA, W_n2,  b_n2,   hbuf, N);
  hipMemsetAsync(menc, 0, (size_t)N * 4, stream);
  hipMemsetAsync(sbuf, 0, (size_t)N * 4, stream);
  hipMemsetAsync(nodeB, 0, (size_t)N * 32 * 4, stream);
  edge_f_k<128,128,30,32,1,true,5><<<gE4,NTH,0,stream>>>(fbuf1, xWni, xWnj, W_f2, attn2, bias2,
                                                         src, dst, fbuf2, scoreb, menc, E);
  softmax_ex_k<<<gEe,NTH,0,stream>>>(scoreb, dst, menc, sbuf, E);
  softmax_norm_k<<<gEe,NTH,0,stream>>>(scoreb, sbuf, dst, E);
  scatter_h_k<30,32,32><<<(int)(((long long)E*30 + NTH-1)/NTH),NTH,0,stream>>>(scoreb, src, dst, hbuf, nodeB, E);

  // ---------------- layer 3: di=30 (stride 32) -> do=64 — only f3 (JSPLIT=2) ----------------
  node_linear_k<30,32,64,64,2,4><<<gN2,NTH,0,stream>>>(nodeB, W_ni3, nullptr, xWni, N);
  node_linear_k<30,32,64,64,2,4><<<gN2,NTH,0,stream>>>(nodeB, W_nj3, nullptr, xWnj, N);
  edge_f_k<30,32,64,64,2,false,4><<<gE2,NTH,0,stream>>>(fbuf2, xWni, xWnj, W_f3, attn3, bias3,
                                                        src, dst, (float*)d_out, nullptr, nullptr, E);
}